// Round 5
// baseline (337.991 us; speedup 1.0000x reference)
//
#include <hip/hip_runtime.h>

// FFF tree-routing MLP, MI355X — fp32 I/O. Round 10: XCD-local subtrees.
//
// R9 post-mortem: phaseB5 WRITE_SIZE=285MB vs 64MB output -> ~220MB scratch
// spills (16 pinned rows ate the 64-VGPR allocation; acc spilled). Pinning
// moves spills, doesn't remove them. phaseA: 3 structurally different inner
// loops (R5/R7/R8) all ~80-115us -> bandwidth wall, not ILP: 786MB of w_in
// rows through L2-miss/LLC at ~10 TB/s. w_in (33.5MB) can't fit a 4MB XCD
// L2 with tokens scattered randomly.
// R10: make the tree fit the L2s. Level-3 subtree = 511 nodes (lv 3-11) =
// 4.18MB = one XCD L2. phaseA0 computes lv 0-2 (7 rows, L1-hot) + bins
// tokens by lv-3 node; scatter8 sorts; phaseA1 descends lv 3-11 with
// subtree g pinned to XCD g (blockIdx&7), x loaded nontemporally so the
// row set stays L2-resident. Dot/reduce instruction-identical (routing
// bit-exact). phaseB reverts verbatim to the proven-232us R5 version
// (VGPR-light, no pins) + nontemporal out stores (cache hint only).

#define D_IN    2048
#define D_OUT   2048
#define DEPTHP1 12
#define N_NODES 4095
#define N_TOK   8192
#define N_LEAF  2048
#define A1_GPB  512   // blocks per subtree group (grid-stride covers rest)

typedef float f4 __attribute__((ext_vector_type(4)));

// ---------------- K1: transpose w_out + zero hist/cnt/hist8/cnt8 -----------
__global__ __launch_bounds__(256) void transpose_wout64z(
    const float* __restrict__ in, float* __restrict__ out,
    int* __restrict__ hc /* hist[2048] cnt[2048] hist8[8] cnt8[8] */) {
    __shared__ float tile[64][65];
    const int fb = blockIdx.y * 64 + blockIdx.x;     // 0..2047
    const int tx = threadIdx.x;                      // 0..63
    const int ty = threadIdx.y;                      // 0..3
    if (fb < 17) {
        const int i = fb * 256 + ty * 64 + tx;
        if (i < 2 * N_LEAF + 16) hc[i] = 0;
    }
    const int n0 = blockIdx.x * 64;
    const int j0 = blockIdx.y * 64;
    const int n = n0 + tx;
#pragma unroll
    for (int k = 0; k < 16; k++) {
        const int r = ty * 16 + k;
        if (n < N_NODES) tile[r][tx] = in[(size_t)(j0 + r) * N_NODES + n];
    }
    __syncthreads();
#pragma unroll
    for (int k = 0; k < 16; k++) {
        const int r = ty * 16 + k;
        const int nn = n0 + r;
        if (nn < N_NODES) out[(size_t)nn * D_OUT + (j0 + tx)] = tile[tx][r];
    }
}

// ---------------- K2: phase A0 — levels 0-2 (L1-hot rows) + lv-3 binning ---
__global__ __launch_bounds__(256) void phaseA0(
    const float* __restrict__ x,      // [N_TOK, D_IN]
    const float* __restrict__ w_in,   // [N_NODES, D_IN]
    float* __restrict__ s_all,        // [N_TOK, 12] raw scores (lv 0-2 here)
    int* __restrict__ grp8,           // [N_TOK] level-3 subtree id 0..7
    int* __restrict__ hist8) {        // [8]
    const int wave  = threadIdx.x >> 6;
    const int lane  = threadIdx.x & 63;
    const int token = blockIdx.x * 4 + wave;

    const f4* xrow = (const f4*)(x + (size_t)token * D_IN);
    f4 xf[8];
#pragma unroll
    for (int c = 0; c < 8; c++) xf[c] = xrow[lane + 64 * c];

    int cur = 0;
#pragma unroll
    for (int l = 0; l < 3; l++) {
        const f4* wrow = (const f4*)(w_in + (size_t)cur * D_IN);
        f4 wv[8];
#pragma unroll
        for (int c = 0; c < 8; c++) wv[c] = wrow[lane + 64 * c];
        float p0 = 0.f, p1 = 0.f, p2 = 0.f, p3 = 0.f;
#pragma unroll
        for (int c = 0; c < 8; c++) {
            float* p = (c < 2) ? &p0 : (c < 4) ? &p1 : (c < 6) ? &p2 : &p3;
            *p += wv[c][0] * xf[c][0] + wv[c][1] * xf[c][1] +
                  wv[c][2] * xf[c][2] + wv[c][3] * xf[c][3];
        }
        float part = (p0 + p1) + (p2 + p3);
#pragma unroll
        for (int off = 32; off >= 1; off >>= 1)
            part += __shfl_xor(part, off, 64);
        const float score = part;
        cur = 2 * cur + 1 + (score >= 0.f ? 1 : 0);
        if (lane == 0) s_all[token * DEPTHP1 + l] = score;
    }
    if (lane == 0) {
        const int g = cur - 7;            // level-3 node, 0..7
        grp8[token] = g;
        atomicAdd(&hist8[g], 1);
    }
}

// ---------------- K3: 8-bucket scatter of token ids ------------------------
__global__ __launch_bounds__(256) void scatter8(
    const int* __restrict__ grp8, const int* __restrict__ hist8,
    int* __restrict__ cnt8, int* __restrict__ order3,
    int* __restrict__ offs8 /*[9]*/) {
    const int t = blockIdx.x * 256 + threadIdx.x;
    int base[8];
    int acc = 0;
#pragma unroll
    for (int k = 0; k < 8; k++) { base[k] = acc; acc += hist8[k]; }
    if (t < 8) offs8[t] = base[t];
    if (t == 8) offs8[8] = N_TOK;
    if (t < N_TOK) {
        const int g = grp8[t];
        const int pos = base[g] + atomicAdd(&cnt8[g], 1);
        order3[pos] = t;
    }
}

// ---------------- K4: phase A1 — levels 3-11, subtree pinned to XCD --------
__global__ __launch_bounds__(256) void phaseA1(
    const float* __restrict__ x,      // [N_TOK, D_IN]
    const float* __restrict__ w_in,   // [N_NODES, D_IN]
    const int* __restrict__ order3,   // [N_TOK] tokens sorted by lv-3 node
    const int* __restrict__ offs8,    // [9]
    float* __restrict__ s_all,        // [N_TOK, 12] raw scores (lv 3-11 here)
    int* __restrict__ leaf,           // [N_TOK]
    int* __restrict__ hist) {         // [N_LEAF]
    const int g    = blockIdx.x & 7;  // subtree == XCD (round-robin dispatch)
    const int idx  = blockIdx.x >> 3; // 0..A1_GPB-1
    const int wave = threadIdx.x >> 6;
    const int lane = threadIdx.x & 63;
    const int beg = offs8[g];
    const int lim = offs8[g + 1];

    for (int slot = beg + idx * 4 + wave; slot < lim; slot += 4 * A1_GPB) {
        const int token = order3[slot];
        const f4* xrow = (const f4*)(x + (size_t)token * D_IN);
        f4 xf[8];
#pragma unroll
        for (int c = 0; c < 8; c++)   // nt: keep x out of the w-row L2 set
            xf[c] = __builtin_nontemporal_load(&xrow[lane + 64 * c]);

        int cur = g + 7;              // level-3 heap node
#pragma unroll
        for (int l = 3; l < DEPTHP1; l++) {
            const f4* wrow = (const f4*)(w_in + (size_t)cur * D_IN);
            f4 wv[8];
#pragma unroll
            for (int c = 0; c < 8; c++) wv[c] = wrow[lane + 64 * c];
            float p0 = 0.f, p1 = 0.f, p2 = 0.f, p3 = 0.f;
#pragma unroll
            for (int c = 0; c < 8; c++) {
                float* p = (c < 2) ? &p0 : (c < 4) ? &p1 : (c < 6) ? &p2 : &p3;
                *p += wv[c][0] * xf[c][0] + wv[c][1] * xf[c][1] +
                      wv[c][2] * xf[c][2] + wv[c][3] * xf[c][3];
            }
            float part = (p0 + p1) + (p2 + p3);
#pragma unroll
            for (int off = 32; off >= 1; off >>= 1)
                part += __shfl_xor(part, off, 64);
            const float score = part;
            cur = 2 * cur + 1 + (score >= 0.f ? 1 : 0);
            if (lane == 0) s_all[token * DEPTHP1 + l] = score;
        }
        if (lane == 0) {
            const int leafid = ((cur - 1) >> 1) - (N_LEAF - 1);
            leaf[token] = leafid;
            atomicAdd(&hist[leafid], 1);
        }
    }
}

// ---------------- K5: exclusive scan over 2048 bins ------------------------
__global__ __launch_bounds__(256) void scan2048(
    const int* __restrict__ hist, int* __restrict__ offsets /*[2049]*/) {
    __shared__ int vals[N_LEAF];
    __shared__ int partial[256];
    const int t = threadIdx.x;
    int sum = 0;
#pragma unroll
    for (int k = 0; k < 8; k++) {
        const int v = hist[t * 8 + k];
        vals[t * 8 + k] = v;
        sum += v;
    }
    partial[t] = sum;
    __syncthreads();
    for (int off = 1; off < 256; off <<= 1) {
        const int v  = partial[t];
        const int vo = (t >= off) ? partial[t - off] : 0;
        __syncthreads();
        partial[t] = v + vo;
        __syncthreads();
    }
    int base = (t > 0) ? partial[t - 1] : 0;
#pragma unroll
    for (int k = 0; k < 8; k++) {
        offsets[t * 8 + k] = base;
        base += vals[t * 8 + k];
    }
    if (t == 255) offsets[N_LEAF] = base;  // == N_TOK
}

// ---------------- K6: scatter tokens; apply gelu HERE ----------------------
__global__ __launch_bounds__(256) void scatter_tokens2(
    const int* __restrict__ leaf, const int* __restrict__ offsets,
    int* __restrict__ cnt, const float* __restrict__ s_all,
    int* __restrict__ order, float* __restrict__ g_sorted) {
    const int t = blockIdx.x * 256 + threadIdx.x;
    if (t < N_TOK) {
        const int lf = leaf[t];
        const int pos = offsets[lf] + atomicAdd(&cnt[lf], 1);
        order[pos] = t;
#pragma unroll
        for (int l = 0; l < DEPTHP1; l++) {
            const float s = s_all[(size_t)t * DEPTHP1 + l];
            const float g = 0.5f * s * (1.0f + erff(s * 0.70710678118654752f));
            g_sorted[(size_t)pos * DEPTHP1 + l] = g;
        }
    }
}

// ---------------- K7: phase B — R5-proven leaf-grouped accumulation --------
__global__ __launch_bounds__(256, 2) void phaseB(
    const float* __restrict__ w_out_t,  // [N_NODES, D_OUT]
    const float* __restrict__ g_sorted, // [N_TOK, 12] leaf-sorted, gelu'd
    const int* __restrict__ order,      // [N_TOK]
    const int* __restrict__ offsets,    // [N_LEAF+1]
    float* __restrict__ out) {          // [N_TOK, D_OUT]
    // XCD swizzle: XCD k (= blockIdx%8) gets contiguous leaves [k*256,(k+1)*256)
    const int lf = ((blockIdx.x & 7) << 8) | (blockIdx.x >> 3);
    const int start = offsets[lf];
    const int end   = offsets[lf + 1];
    if (start == end) return;
    const int t = threadIdx.x;           // owns cols [8t, 8t+8)

    int nodes[DEPTHP1];
    const int L = lf + N_LEAF;           // 1-based leaf heap index
#pragma unroll
    for (int l = 0; l < DEPTHP1; l++) nodes[l] = (L >> (DEPTHP1 - 1 - l)) - 1;

    for (int cs = start; cs < end; cs += 8) {
        const int T = end - cs;          // effective count this chunk: min(T,8)
        float acc[8][8];
#pragma unroll
        for (int tt = 0; tt < 8; tt++)
#pragma unroll
            for (int k = 0; k < 8; k++) acc[tt][k] = 0.f;

#pragma unroll
        for (int l = 0; l < DEPTHP1; l++) {
            const float4* wr = (const float4*)(w_out_t + (size_t)nodes[l] * D_OUT);
            const float4 w0 = wr[t * 2 + 0];
            const float4 w1 = wr[t * 2 + 1];
#pragma unroll
            for (int tt = 0; tt < 8; tt++) {
                const float g = (tt < T)
                    ? g_sorted[(size_t)(cs + tt) * DEPTHP1 + l] : 0.f;
                acc[tt][0] += g * w0.x; acc[tt][1] += g * w0.y;
                acc[tt][2] += g * w0.z; acc[tt][3] += g * w0.w;
                acc[tt][4] += g * w1.x; acc[tt][5] += g * w1.y;
                acc[tt][6] += g * w1.z; acc[tt][7] += g * w1.w;
            }
        }
#pragma unroll
        for (int tt = 0; tt < 8; tt++) {
            if (tt < T) {
                const int tok = order[cs + tt];
                f4* po = (f4*)(out + (size_t)tok * D_OUT + t * 8);
                f4 o0, o1;
                o0[0] = acc[tt][0]; o0[1] = acc[tt][1];
                o0[2] = acc[tt][2]; o0[3] = acc[tt][3];
                o1[0] = acc[tt][4]; o1[1] = acc[tt][5];
                o1[2] = acc[tt][6]; o1[3] = acc[tt][7];
                __builtin_nontemporal_store(o0, po);      // out never re-read:
                __builtin_nontemporal_store(o1, po + 1);  // keep L2 for w rows
            }
        }
    }
}

// ---------------- Fallback kernels (small workspace) -----------------------
__global__ __launch_bounds__(256) void transpose_wout64(
    const float* __restrict__ in, float* __restrict__ out) {
    __shared__ float tile[64][65];
    const int n0 = blockIdx.x * 64;
    const int j0 = blockIdx.y * 64;
    const int tx = threadIdx.x;
    const int ty = threadIdx.y;
    const int n = n0 + tx;
#pragma unroll
    for (int k = 0; k < 16; k++) {
        const int r = ty * 16 + k;
        if (n < N_NODES) tile[r][tx] = in[(size_t)(j0 + r) * N_NODES + n];
    }
    __syncthreads();
#pragma unroll
    for (int k = 0; k < 16; k++) {
        const int r = ty * 16 + k;
        const int nn = n0 + r;
        if (nn < N_NODES) out[(size_t)nn * D_OUT + (j0 + tx)] = tile[tx][r];
    }
}

template <bool TRANSPOSED>
__global__ __launch_bounds__(256) void fff_fused(
    const float* __restrict__ x, const float* __restrict__ w_in,
    const float* __restrict__ w_out, float* __restrict__ out) {
    const int wave  = threadIdx.x >> 6;
    const int lane  = threadIdx.x & 63;
    const int token = blockIdx.x * 4 + wave;
    const float4* xrow = (const float4*)(x + (size_t)token * D_IN);
    float xf[32];
#pragma unroll
    for (int c = 0; c < 8; c++) {
        float4 xc = xrow[lane + 64 * c];
        xf[c * 4 + 0] = xc.x; xf[c * 4 + 1] = xc.y;
        xf[c * 4 + 2] = xc.z; xf[c * 4 + 3] = xc.w;
    }
    float acc[32];
#pragma unroll
    for (int k = 0; k < 32; k++) acc[k] = 0.f;
    int cur = 0;
#pragma unroll
    for (int l = 0; l < DEPTHP1; l++) {
        const float4* wrow = (const float4*)(w_in + (size_t)cur * D_IN);
        float part = 0.f;
#pragma unroll
        for (int c = 0; c < 8; c++) {
            float4 wc = wrow[lane + 64 * c];
            part += wc.x * xf[c * 4 + 0]; part += wc.y * xf[c * 4 + 1];
            part += wc.z * xf[c * 4 + 2]; part += wc.w * xf[c * 4 + 3];
        }
#pragma unroll
        for (int off = 32; off >= 1; off >>= 1) part += __shfl_xor(part, off, 64);
        const float score = part;
        const float g = 0.5f * score * (1.0f + erff(score * 0.70710678118654752f));
        if (TRANSPOSED) {
            const float4* orow = (const float4*)(w_out + (size_t)cur * D_OUT);
#pragma unroll
            for (int c = 0; c < 8; c++) {
                float4 oc = orow[lane + 64 * c];
                acc[c * 4 + 0] += g * oc.x; acc[c * 4 + 1] += g * oc.y;
                acc[c * 4 + 2] += g * oc.z; acc[c * 4 + 3] += g * oc.w;
            }
        } else {
#pragma unroll
            for (int c = 0; c < 8; c++)
#pragma unroll
                for (int k = 0; k < 4; k++) {
                    const int j = (lane + 64 * c) * 4 + k;
                    acc[c * 4 + k] += g * w_out[(size_t)j * N_NODES + cur];
                }
        }
        cur = 2 * cur + 1 + (score >= 0.f ? 1 : 0);
    }
    float4* outrow = (float4*)(out + (size_t)token * D_OUT);
#pragma unroll
    for (int c = 0; c < 8; c++) {
        float4 o;
        o.x = acc[c * 4 + 0]; o.y = acc[c * 4 + 1];
        o.z = acc[c * 4 + 2]; o.w = acc[c * 4 + 3];
        outrow[lane + 64 * c] = o;
    }
}

extern "C" void kernel_launch(void* const* d_in, const int* in_sizes, int n_in,
                              void* d_out, int out_size, void* d_ws, size_t ws_size,
                              hipStream_t stream) {
    (void)in_sizes; (void)n_in; (void)out_size;
    const float* x     = (const float*)d_in[0];
    const float* w_in  = (const float*)d_in[1];
    const float* w_out = (const float*)d_in[2];
    float* out = (float*)d_out;

    const size_t wt_bytes   = (size_t)N_NODES * D_OUT * sizeof(float);   // 33.546 MB
    const size_t s_bytes    = (size_t)N_TOK * DEPTHP1 * sizeof(float);   // 393 KB
    const size_t leaf_bytes = (size_t)N_TOK * sizeof(int);
    const size_t ord_bytes  = (size_t)N_TOK * sizeof(int);
    const size_t hc_bytes   = (size_t)(2 * N_LEAF + 16) * sizeof(int);   // hist,cnt,h8,c8
    const size_t off8_bytes = 16 * sizeof(int);                          // offs8 (padded)
    const size_t offs_bytes = (size_t)(N_LEAF + 1) * sizeof(int);
    const size_t gs_bytes   = s_bytes;                                   // g_sorted
    const size_t grp_bytes  = (size_t)N_TOK * sizeof(int);
    const size_t o3_bytes   = (size_t)N_TOK * sizeof(int);
    const size_t need = wt_bytes + s_bytes + leaf_bytes + ord_bytes +
                        hc_bytes + off8_bytes + offs_bytes + gs_bytes +
                        grp_bytes + o3_bytes + 64;

    if (ws_size >= need) {
        char* p = (char*)d_ws;
        float* w_out_t  = (float*)p;  p += wt_bytes;
        float* s_all    = (float*)p;  p += s_bytes;
        float* g_sorted = (float*)p;  p += gs_bytes;
        int*   leaf     = (int*)p;    p += leaf_bytes;
        int*   order    = (int*)p;    p += ord_bytes;
        int*   hist     = (int*)p;    p += 2 * N_LEAF * sizeof(int) - N_LEAF * sizeof(int);
        // (hist and cnt are the first 2*N_LEAF ints of hc; lay out explicitly:)
        p = (char*)hist;  // rewind: hist starts here
        int*   cnt      = hist + N_LEAF;
        int*   hist8    = hist + 2 * N_LEAF;
        int*   cnt8     = hist8 + 8;
        p = (char*)(hist) + hc_bytes;
        int*   offs8    = (int*)p;    p += off8_bytes;
        int*   offsets  = (int*)p;    p += offs_bytes;
        int*   grp8     = (int*)p;    p += grp_bytes;
        int*   order3   = (int*)p;

        // 1) transpose w_out (+ zero hist/cnt/hist8/cnt8)
        transpose_wout64z<<<dim3(64, 32), dim3(64, 4), 0, stream>>>(
            w_out, w_out_t, hist);
        // 2) levels 0-2 + level-3 binning
        phaseA0<<<N_TOK / 4, 256, 0, stream>>>(x, w_in, s_all, grp8, hist8);
        // 3) 8-bucket token sort
        scatter8<<<N_TOK / 256, 256, 0, stream>>>(grp8, hist8, cnt8, order3,
                                                  offs8);
        // 4) levels 3-11, subtree-per-XCD
        phaseA1<<<8 * A1_GPB, 256, 0, stream>>>(x, w_in, order3, offs8,
                                                s_all, leaf, hist);
        // 5-7) leaf sort + gelu + output accumulation
        scan2048<<<1, 256, 0, stream>>>(hist, offsets);
        scatter_tokens2<<<N_TOK / 256, 256, 0, stream>>>(leaf, offsets, cnt,
                                                         s_all, order, g_sorted);
        phaseB<<<N_LEAF, 256, 0, stream>>>(w_out_t, g_sorted, order, offsets,
                                           out);
    } else if (ws_size >= wt_bytes) {
        float* w_out_t = (float*)d_ws;
        transpose_wout64<<<dim3((N_NODES + 63) / 64, D_OUT / 64), dim3(64, 4),
                           0, stream>>>(w_out, w_out_t);
        fff_fused<true><<<N_TOK / 4, 256, 0, stream>>>(x, w_in, w_out_t, out);
    } else {
        fff_fused<false><<<N_TOK / 4, 256, 0, stream>>>(x, w_in, w_out, out);
    }
}

// Round 6
// 240.919 us; speedup vs baseline: 1.4029x; 1.4029x over previous
//
#include <hip/hip_runtime.h>

// FFF tree-routing MLP, MI355X — fp32 I/O. Round 11: sorted col-tile phaseB.
//
// R10 post-mortem: phaseA0 (3 levels, 56KB L1-hot w-set) took 104us == every
// 12-level phaseA -> the level loop is NOT phaseA's cost; its hot-8 atomic
// (8192 wave-atomics on one line, ~30cy serialized ~ 250K cy) dominates, and
// the shared x-load/launch shape explains the rest. Locality split abandoned;
// total regressed 232->338 from extra passes. Lessons: never funnel 8192
// atomics to <128 lines; stop rewriting phaseA's inner loop.
// What DOES model cleanly: R0-phaseB reads 2048 blocks x 12 rows x 8KB =
// 196MB of w_out_t re-reads at the measured ~2 TB/s cache rate ~= its 105us.
// R11 = proven-232 R0 pipeline with ONE swap: phaseB -> phaseB_cols, which
// walks tokens in leaf-sorted order, col-tiled (512 blocks = 8 XCDs x 32
// token-ranges x 2 col-halves). Consecutive tokens share their leaf's 12
// rows (held in ~48 VGPRs per leaf-run); sibling leaves share 11/12 rows ->
// row set stays L1/L2-resident, w_out_t pulled ~once (33.5MB). g loads are
// block-uniform (scalar). No LDS, no barriers, no atomics, no spill risk.
// FP order per output element identical to R0 phaseB (ascending-l FMA into
// zero-init acc). scatter additionally emits lf_sorted.

#define D_IN    2048
#define D_OUT   2048
#define DEPTHP1 12
#define N_NODES 4095
#define N_TOK   8192
#define N_LEAF  2048

typedef float f4 __attribute__((ext_vector_type(4)));

// ---------------- K1: transpose w_out [D_OUT, N_NODES] -> [N_NODES, D_OUT] --
__global__ __launch_bounds__(256) void transpose_wout64(
    const float* __restrict__ in, float* __restrict__ out) {
    __shared__ float tile[64][65];
    const int n0 = blockIdx.x * 64;
    const int j0 = blockIdx.y * 64;
    const int tx = threadIdx.x;       // 0..63
    const int ty = threadIdx.y;       // 0..3
    const int n = n0 + tx;
#pragma unroll
    for (int k = 0; k < 16; k++) {
        const int r = ty * 16 + k;    // 0..63
        if (n < N_NODES) tile[r][tx] = in[(size_t)(j0 + r) * N_NODES + n];
    }
    __syncthreads();
#pragma unroll
    for (int k = 0; k < 16; k++) {
        const int r = ty * 16 + k;
        const int nn = n0 + r;
        if (nn < N_NODES) out[(size_t)nn * D_OUT + (j0 + tx)] = tile[tx][r];
    }
}

// ---------------- K2: phase A — path + gelu(logit) per token (R0-proven) ---
__global__ __launch_bounds__(256) void phaseA(
    const float* __restrict__ x,      // [N_TOK, D_IN]
    const float* __restrict__ w_in,   // [N_NODES, D_IN]
    float* __restrict__ g_all,        // [N_TOK, 12]
    int* __restrict__ leaf,           // [N_TOK]
    int* __restrict__ hist) {         // [N_LEAF]
    extern __shared__ float xs[];     // 4 waves x 2048 floats = 32 KB
    const int wave  = threadIdx.x >> 6;
    const int lane  = threadIdx.x & 63;
    const int token = blockIdx.x * 4 + wave;

    // Stage this token's x row into the wave-private LDS slice (once).
    float4* xw = (float4*)(xs) + wave * (D_IN / 4);
    const float4* xrow = (const float4*)(x + (size_t)token * D_IN);
#pragma unroll
    for (int c = 0; c < 8; c++) xw[lane + 64 * c] = xrow[lane + 64 * c];
    // Same-wave produce->consume; compiler inserts lgkmcnt wait. No barrier.

    int cur = 0;
#pragma unroll
    for (int l = 0; l < DEPTHP1; l++) {
        const float4* wrow = (const float4*)(w_in + (size_t)cur * D_IN);
        float p0 = 0.f, p1 = 0.f, p2 = 0.f, p3 = 0.f;
#pragma unroll
        for (int c = 0; c < 8; c++) {
            const float4 wc = wrow[lane + 64 * c];
            const float4 xc = xw[lane + 64 * c];
            float* p = (c < 2) ? &p0 : (c < 4) ? &p1 : (c < 6) ? &p2 : &p3;
            *p += wc.x * xc.x + wc.y * xc.y + wc.z * xc.z + wc.w * xc.w;
        }
        float part = (p0 + p1) + (p2 + p3);
#pragma unroll
        for (int off = 32; off >= 1; off >>= 1)
            part += __shfl_xor(part, off, 64);
        const float score = part;
        // Advance the path first: next-level loads depend only on `cur`.
        cur = 2 * cur + 1 + (score >= 0.f ? 1 : 0);
        const float g = 0.5f * score * (1.0f + erff(score * 0.70710678118654752f));
        if (lane == 0) g_all[token * DEPTHP1 + l] = g;
    }
    if (lane == 0) {
        const int leafid = ((cur - 1) >> 1) - (N_LEAF - 1);  // level-11 node id
        leaf[token] = leafid;
        atomicAdd(&hist[leafid], 1);                         // 2048 bins: spread
    }
}

// ---------------- K3: zero hist + cnt (contiguous 2*N_LEAF ints) -----------
__global__ __launch_bounds__(256) void init_counts(int* __restrict__ p) {
    const int i = blockIdx.x * 256 + threadIdx.x;
    if (i < 2 * N_LEAF) p[i] = 0;
}

// ---------------- K4: exclusive scan over 2048 bins ------------------------
__global__ __launch_bounds__(256) void scan2048(
    const int* __restrict__ hist, int* __restrict__ offsets /*[2049]*/) {
    __shared__ int vals[N_LEAF];
    __shared__ int partial[256];
    const int t = threadIdx.x;
    int sum = 0;
#pragma unroll
    for (int k = 0; k < 8; k++) {
        const int v = hist[t * 8 + k];
        vals[t * 8 + k] = v;
        sum += v;
    }
    partial[t] = sum;
    __syncthreads();
    for (int off = 1; off < 256; off <<= 1) {
        const int v  = partial[t];
        const int vo = (t >= off) ? partial[t - off] : 0;
        __syncthreads();
        partial[t] = v + vo;
        __syncthreads();
    }
    int base = (t > 0) ? partial[t - 1] : 0;
#pragma unroll
    for (int k = 0; k < 8; k++) {
        offsets[t * 8 + k] = base;
        base += vals[t * 8 + k];
    }
    if (t == 255) offsets[N_LEAF] = base;  // == N_TOK
}

// ---------------- K5: scatter tokens + g into leaf-sorted order ------------
__global__ __launch_bounds__(256) void scatter_tokens(
    const int* __restrict__ leaf, const int* __restrict__ offsets,
    int* __restrict__ cnt, const float* __restrict__ g_all,
    int* __restrict__ order, float* __restrict__ g_sorted,
    int* __restrict__ lf_sorted) {
    const int t = blockIdx.x * 256 + threadIdx.x;
    if (t < N_TOK) {
        const int lf = leaf[t];
        const int pos = offsets[lf] + atomicAdd(&cnt[lf], 1);
        order[pos] = t;
        lf_sorted[pos] = lf;
#pragma unroll
        for (int l = 0; l < DEPTHP1; l++)
            g_sorted[(size_t)pos * DEPTHP1 + l] = g_all[(size_t)t * DEPTHP1 + l];
    }
}

// ---------------- K6: phase B — sorted-order col-tile streaming ------------
// 512 blocks = 8 XCDs x {32 token-ranges x 2 col-halves}. XCD k owns sorted
// positions [k*1024,(k+1)*1024): a 256-leaf subtree whose row-slice union
// (~511 rows x 8KB across both halves) fits k's 4MB L2. Within a leaf-run
// the 12 row-f4s live in registers; tokens stream over them.
__global__ __launch_bounds__(256) void phaseB_cols(
    const float* __restrict__ w_out_t,   // [N_NODES, D_OUT]
    const float* __restrict__ g_sorted,  // [N_TOK, 12] leaf-sorted, gelu'd
    const int* __restrict__ order,       // [N_TOK]
    const int* __restrict__ lf_sorted,   // [N_TOK]
    float* __restrict__ out) {           // [N_TOK, D_OUT]
    const int b   = blockIdx.x;
    const int xcd = b & 7;
    const int j   = b >> 3;              // 0..63
    const int tr  = xcd * 32 + (j >> 1); // 0..255 token-range (32 tokens)
    const int ct  = j & 1;               // column half
    const int t   = threadIdx.x;         // f4 column within half
    const size_t coff = (size_t)ct * 1024 + (size_t)t * 4;

    const int start = tr * 32;
    const int end   = start + 32;

    int pos = start;
    while (pos < end) {
        const int lf = lf_sorted[pos];   // block-uniform (scalar)
        const int L  = lf + N_LEAF;      // 1-based leaf heap index
        f4 w[DEPTHP1];                   // this leaf's 12 row-f4s, in VGPRs
#pragma unroll
        for (int l = 0; l < DEPTHP1; l++) {
            const int node = (L >> (DEPTHP1 - 1 - l)) - 1;
            w[l] = *(const f4*)(w_out_t + (size_t)node * D_OUT + coff);
        }
        do {
            const int tok = order[pos];                       // scalar
            const float* gp = g_sorted + (size_t)pos * DEPTHP1;
            f4 acc = {0.f, 0.f, 0.f, 0.f};
#pragma unroll
            for (int l = 0; l < DEPTHP1; l++)
                acc += gp[l] * w[l];     // ascending l: same FP order as R0
            *(f4*)(out + (size_t)tok * D_OUT + coff) = acc;
            pos++;
        } while (pos < end && lf_sorted[pos] == lf);
    }
}

// ---------------- Fallback: round-2 fused kernel (ws too small) ------------
template <bool TRANSPOSED>
__global__ __launch_bounds__(256) void fff_fused(
    const float* __restrict__ x, const float* __restrict__ w_in,
    const float* __restrict__ w_out, float* __restrict__ out) {
    const int wave  = threadIdx.x >> 6;
    const int lane  = threadIdx.x & 63;
    const int token = blockIdx.x * 4 + wave;
    const float4* xrow = (const float4*)(x + (size_t)token * D_IN);
    float xf[32];
#pragma unroll
    for (int c = 0; c < 8; c++) {
        float4 xc = xrow[lane + 64 * c];
        xf[c * 4 + 0] = xc.x; xf[c * 4 + 1] = xc.y;
        xf[c * 4 + 2] = xc.z; xf[c * 4 + 3] = xc.w;
    }
    float acc[32];
#pragma unroll
    for (int k = 0; k < 32; k++) acc[k] = 0.f;
    int cur = 0;
#pragma unroll
    for (int l = 0; l < DEPTHP1; l++) {
        const float4* wrow = (const float4*)(w_in + (size_t)cur * D_IN);
        float part = 0.f;
#pragma unroll
        for (int c = 0; c < 8; c++) {
            float4 wc = wrow[lane + 64 * c];
            part += wc.x * xf[c * 4 + 0]; part += wc.y * xf[c * 4 + 1];
            part += wc.z * xf[c * 4 + 2]; part += wc.w * xf[c * 4 + 3];
        }
#pragma unroll
        for (int off = 32; off >= 1; off >>= 1) part += __shfl_xor(part, off, 64);
        const float score = part;
        const float g = 0.5f * score * (1.0f + erff(score * 0.70710678118654752f));
        if (TRANSPOSED) {
            const float4* orow = (const float4*)(w_out + (size_t)cur * D_OUT);
#pragma unroll
            for (int c = 0; c < 8; c++) {
                float4 oc = orow[lane + 64 * c];
                acc[c * 4 + 0] += g * oc.x; acc[c * 4 + 1] += g * oc.y;
                acc[c * 4 + 2] += g * oc.z; acc[c * 4 + 3] += g * oc.w;
            }
        } else {
#pragma unroll
            for (int c = 0; c < 8; c++)
#pragma unroll
                for (int k = 0; k < 4; k++) {
                    const int j = (lane + 64 * c) * 4 + k;
                    acc[c * 4 + k] += g * w_out[(size_t)j * N_NODES + cur];
                }
        }
        cur = 2 * cur + 1 + (score >= 0.f ? 1 : 0);
    }
    float4* outrow = (float4*)(out + (size_t)token * D_OUT);
#pragma unroll
    for (int c = 0; c < 8; c++) {
        float4 o;
        o.x = acc[c * 4 + 0]; o.y = acc[c * 4 + 1];
        o.z = acc[c * 4 + 2]; o.w = acc[c * 4 + 3];
        outrow[lane + 64 * c] = o;
    }
}

extern "C" void kernel_launch(void* const* d_in, const int* in_sizes, int n_in,
                              void* d_out, int out_size, void* d_ws, size_t ws_size,
                              hipStream_t stream) {
    (void)in_sizes; (void)n_in; (void)out_size;
    const float* x     = (const float*)d_in[0];
    const float* w_in  = (const float*)d_in[1];
    const float* w_out = (const float*)d_in[2];
    float* out = (float*)d_out;

    const size_t wt_bytes   = (size_t)N_NODES * D_OUT * sizeof(float);   // 33.546 MB
    const size_t g_bytes    = (size_t)N_TOK * DEPTHP1 * sizeof(float);   // 393 KB
    const size_t leaf_bytes = (size_t)N_TOK * sizeof(int);
    const size_t ord_bytes  = (size_t)N_TOK * sizeof(int);
    const size_t hist_bytes = (size_t)N_LEAF * sizeof(int);
    const size_t cnt_bytes  = (size_t)N_LEAF * sizeof(int);
    const size_t offs_bytes = (size_t)(N_LEAF + 1) * sizeof(int);
    const size_t gs_bytes   = g_bytes;                                   // g_sorted
    const size_t lfs_bytes  = (size_t)N_TOK * sizeof(int);               // lf_sorted
    const size_t need = wt_bytes + g_bytes + leaf_bytes + ord_bytes +
                        hist_bytes + cnt_bytes + offs_bytes + gs_bytes +
                        lfs_bytes + 64;

    if (ws_size >= need) {
        char* p = (char*)d_ws;
        float* w_out_t  = (float*)p;  p += wt_bytes;
        float* g_all    = (float*)p;  p += g_bytes;
        int*   leaf     = (int*)p;    p += leaf_bytes;
        int*   order    = (int*)p;    p += ord_bytes;
        int*   hist     = (int*)p;    p += hist_bytes;   // hist+cnt contiguous
        int*   cnt      = (int*)p;    p += cnt_bytes;
        int*   offsets  = (int*)p;    p += offs_bytes;
        float* g_sorted = (float*)p;  p += gs_bytes;
        int*   lf_sorted= (int*)p;

        init_counts<<<(2 * N_LEAF + 255) / 256, 256, 0, stream>>>(hist);
        transpose_wout64<<<dim3((N_NODES + 63) / 64, D_OUT / 64), dim3(64, 4),
                           0, stream>>>(w_out, w_out_t);
        phaseA<<<N_TOK / 4, 256, 4 * D_IN * sizeof(float), stream>>>(
            x, w_in, g_all, leaf, hist);
        scan2048<<<1, 256, 0, stream>>>(hist, offsets);
        scatter_tokens<<<N_TOK / 256, 256, 0, stream>>>(leaf, offsets, cnt,
                                                        g_all, order, g_sorted,
                                                        lf_sorted);
        phaseB_cols<<<512, 256, 0, stream>>>(w_out_t, g_sorted, order,
                                             lf_sorted, out);
    } else if (ws_size >= wt_bytes) {
        float* w_out_t = (float*)d_ws;
        transpose_wout64<<<dim3((N_NODES + 63) / 64, D_OUT / 64), dim3(64, 4),
                           0, stream>>>(w_out, w_out_t);
        fff_fused<true><<<N_TOK / 4, 256, 0, stream>>>(x, w_in, w_out_t, out);
    } else {
        fff_fused<false><<<N_TOK / 4, 256, 0, stream>>>(x, w_in, w_out, out);
    }
}

// Round 7
// 240.890 us; speedup vs baseline: 1.4031x; 1.0001x over previous
//
#include <hip/hip_runtime.h>

// FFF tree-routing MLP, MI355X — fp32 I/O. Round 12: global_load_lds phaseA.
//
// R11 post-mortem: phaseB_cols WORKED (dropped out of top-5; sort-locality
// model for w_out_t confirmed). phaseA now #1 at 67.7us. Four rounds showed
// the 8 w-loads/level serialize because 8 f4 dests need 32 VGPRs the
// allocator never grants (48-ceiling; asm-forcing just spilled x). Fix that
// sidesteps the allocator: global_load_lds issues all 8 loads with ZERO dest
// VGPRs into a wave-private 8KB LDS w-buffer; one vmcnt(0); then 16
// ds_read_b128 feed the same dot. Ordering is data-dependence-safe (next
// level's address depends on this level's score). 64-thread blocks, 16KB
// LDS -> 10 waves/CU. phaseB_cols: 512->2048 blocks (8-token ranges, same
// XCD-contiguous mapping) for 8 waves/SIMD + nontemporal out stores.
// All FP accumulation/reduction orders bit-identical to the passing R11.

#define D_IN    2048
#define D_OUT   2048
#define DEPTHP1 12
#define N_NODES 4095
#define N_TOK   8192
#define N_LEAF  2048

typedef float f4 __attribute__((ext_vector_type(4)));

#define GLDS16(gp, lp)                                                  \
    __builtin_amdgcn_global_load_lds(                                   \
        (const __attribute__((address_space(1))) void*)(gp),            \
        (__attribute__((address_space(3))) void*)(lp), 16, 0, 0)

// ---------------- K1: transpose w_out [D_OUT, N_NODES] -> [N_NODES, D_OUT] --
__global__ __launch_bounds__(256) void transpose_wout64(
    const float* __restrict__ in, float* __restrict__ out) {
    __shared__ float tile[64][65];
    const int n0 = blockIdx.x * 64;
    const int j0 = blockIdx.y * 64;
    const int tx = threadIdx.x;       // 0..63
    const int ty = threadIdx.y;       // 0..3
    const int n = n0 + tx;
#pragma unroll
    for (int k = 0; k < 16; k++) {
        const int r = ty * 16 + k;    // 0..63
        if (n < N_NODES) tile[r][tx] = in[(size_t)(j0 + r) * N_NODES + n];
    }
    __syncthreads();
#pragma unroll
    for (int k = 0; k < 16; k++) {
        const int r = ty * 16 + k;
        const int nn = n0 + r;
        if (nn < N_NODES) out[(size_t)nn * D_OUT + (j0 + tx)] = tile[tx][r];
    }
}

// ---------------- K2: phase A — tree descent, w staged via global_load_lds --
__global__ __launch_bounds__(64) void phaseA_gl(
    const float* __restrict__ x,      // [N_TOK, D_IN]
    const float* __restrict__ w_in,   // [N_NODES, D_IN]
    float* __restrict__ g_all,        // [N_TOK, 12]
    int* __restrict__ leaf,           // [N_TOK]
    int* __restrict__ hist) {         // [N_LEAF]
    __shared__ float xs[D_IN];        // 8 KB: this token's x row
    __shared__ float wb[D_IN];        // 8 KB: current level's w row
    const int lane  = threadIdx.x;    // 0..63 (one wave per block)
    const int token = blockIdx.x;

    // Stage x row: 8 async 1KB chunks, zero dest VGPRs.
    const float* xrow = x + (size_t)token * D_IN;
#pragma unroll
    for (int c = 0; c < 8; c++)
        GLDS16(xrow + 4 * (lane + 64 * c), xs + c * 256);

    const f4* xl = (const f4*)xs;
    const f4* wl = (const f4*)wb;

    int cur = 0;
#pragma unroll
    for (int l = 0; l < DEPTHP1; l++) {
        const float* wrow = w_in + (size_t)cur * D_IN;
        // 8 async loads of the w row into LDS: one round-trip per level,
        // no destination registers for the allocator to ration.
#pragma unroll
        for (int c = 0; c < 8; c++)
            GLDS16(wrow + 4 * (lane + 64 * c), wb + c * 256);
        asm volatile("s_waitcnt vmcnt(0)" ::: "memory");
        __builtin_amdgcn_sched_barrier(0);

        float p0 = 0.f, p1 = 0.f, p2 = 0.f, p3 = 0.f;
#pragma unroll
        for (int c = 0; c < 8; c++) {
            const f4 wc = wl[lane + 64 * c];
            const f4 xc = xl[lane + 64 * c];
            float* p = (c < 2) ? &p0 : (c < 4) ? &p1 : (c < 6) ? &p2 : &p3;
            *p += wc[0] * xc[0] + wc[1] * xc[1] + wc[2] * xc[2] + wc[3] * xc[3];
        }
        float part = (p0 + p1) + (p2 + p3);
#pragma unroll
        for (int off = 32; off >= 1; off >>= 1)
            part += __shfl_xor(part, off, 64);
        const float score = part;
        // Advance the path first: next-level loads depend only on `cur`.
        cur = 2 * cur + 1 + (score >= 0.f ? 1 : 0);
        const float g = 0.5f * score * (1.0f + erff(score * 0.70710678118654752f));
        if (lane == 0) g_all[token * DEPTHP1 + l] = g;
    }
    if (lane == 0) {
        const int leafid = ((cur - 1) >> 1) - (N_LEAF - 1);  // level-11 node id
        leaf[token] = leafid;
        atomicAdd(&hist[leafid], 1);                         // 2048 bins: spread
    }
}

// ---------------- K3: zero hist + cnt (contiguous 2*N_LEAF ints) -----------
__global__ __launch_bounds__(256) void init_counts(int* __restrict__ p) {
    const int i = blockIdx.x * 256 + threadIdx.x;
    if (i < 2 * N_LEAF) p[i] = 0;
}

// ---------------- K4: exclusive scan over 2048 bins ------------------------
__global__ __launch_bounds__(256) void scan2048(
    const int* __restrict__ hist, int* __restrict__ offsets /*[2049]*/) {
    __shared__ int vals[N_LEAF];
    __shared__ int partial[256];
    const int t = threadIdx.x;
    int sum = 0;
#pragma unroll
    for (int k = 0; k < 8; k++) {
        const int v = hist[t * 8 + k];
        vals[t * 8 + k] = v;
        sum += v;
    }
    partial[t] = sum;
    __syncthreads();
    for (int off = 1; off < 256; off <<= 1) {
        const int v  = partial[t];
        const int vo = (t >= off) ? partial[t - off] : 0;
        __syncthreads();
        partial[t] = v + vo;
        __syncthreads();
    }
    int base = (t > 0) ? partial[t - 1] : 0;
#pragma unroll
    for (int k = 0; k < 8; k++) {
        offsets[t * 8 + k] = base;
        base += vals[t * 8 + k];
    }
    if (t == 255) offsets[N_LEAF] = base;  // == N_TOK
}

// ---------------- K5: scatter tokens + g into leaf-sorted order ------------
__global__ __launch_bounds__(256) void scatter_tokens(
    const int* __restrict__ leaf, const int* __restrict__ offsets,
    int* __restrict__ cnt, const float* __restrict__ g_all,
    int* __restrict__ order, float* __restrict__ g_sorted,
    int* __restrict__ lf_sorted) {
    const int t = blockIdx.x * 256 + threadIdx.x;
    if (t < N_TOK) {
        const int lf = leaf[t];
        const int pos = offsets[lf] + atomicAdd(&cnt[lf], 1);
        order[pos] = t;
        lf_sorted[pos] = lf;
#pragma unroll
        for (int l = 0; l < DEPTHP1; l++)
            g_sorted[(size_t)pos * DEPTHP1 + l] = g_all[(size_t)t * DEPTHP1 + l];
    }
}

// ---------------- K6: phase B — sorted-order col-tile streaming ------------
// 2048 blocks = 8 XCDs x {128 token-ranges(8) x 2 col-halves}. XCD k owns
// sorted positions [k*1024,(k+1)*1024): a 256-leaf subtree whose row-slice
// union (~511 rows x 8KB) fits k's 4MB L2. Within a leaf-run the 12 row-f4s
// live in registers; tokens stream over them. 8 waves/SIMD device-wide.
__global__ __launch_bounds__(256) void phaseB_cols(
    const float* __restrict__ w_out_t,   // [N_NODES, D_OUT]
    const float* __restrict__ g_sorted,  // [N_TOK, 12] leaf-sorted, gelu'd
    const int* __restrict__ order,       // [N_TOK]
    const int* __restrict__ lf_sorted,   // [N_TOK]
    float* __restrict__ out) {           // [N_TOK, D_OUT]
    const int b   = blockIdx.x;
    const int xcd = b & 7;
    const int j   = b >> 3;               // 0..255
    const int tr  = xcd * 128 + (j >> 1); // 0..1023 token-range (8 tokens)
    const int ct  = j & 1;                // column half
    const int t   = threadIdx.x;          // f4 column within half
    const size_t coff = (size_t)ct * 1024 + (size_t)t * 4;

    const int start = tr * 8;
    const int end   = start + 8;

    int pos = start;
    while (pos < end) {
        const int lf = lf_sorted[pos];    // block-uniform (scalar)
        const int L  = lf + N_LEAF;       // 1-based leaf heap index
        f4 w[DEPTHP1];                    // this leaf's 12 row-f4s, in VGPRs
#pragma unroll
        for (int l = 0; l < DEPTHP1; l++) {
            const int node = (L >> (DEPTHP1 - 1 - l)) - 1;
            w[l] = *(const f4*)(w_out_t + (size_t)node * D_OUT + coff);
        }
        do {
            const int tok = order[pos];                       // scalar
            const float* gp = g_sorted + (size_t)pos * DEPTHP1;
            f4 acc = {0.f, 0.f, 0.f, 0.f};
#pragma unroll
            for (int l = 0; l < DEPTHP1; l++)
                acc += gp[l] * w[l];      // ascending l: same FP order as R11
            __builtin_nontemporal_store(
                acc, (f4*)(out + (size_t)tok * D_OUT + coff));
            pos++;
        } while (pos < end && lf_sorted[pos] == lf);
    }
}

// ---------------- Fallback: round-2 fused kernel (ws too small) ------------
template <bool TRANSPOSED>
__global__ __launch_bounds__(256) void fff_fused(
    const float* __restrict__ x, const float* __restrict__ w_in,
    const float* __restrict__ w_out, float* __restrict__ out) {
    const int wave  = threadIdx.x >> 6;
    const int lane  = threadIdx.x & 63;
    const int token = blockIdx.x * 4 + wave;
    const float4* xrow = (const float4*)(x + (size_t)token * D_IN);
    float xf[32];
#pragma unroll
    for (int c = 0; c < 8; c++) {
        float4 xc = xrow[lane + 64 * c];
        xf[c * 4 + 0] = xc.x; xf[c * 4 + 1] = xc.y;
        xf[c * 4 + 2] = xc.z; xf[c * 4 + 3] = xc.w;
    }
    float acc[32];
#pragma unroll
    for (int k = 0; k < 32; k++) acc[k] = 0.f;
    int cur = 0;
#pragma unroll
    for (int l = 0; l < DEPTHP1; l++) {
        const float4* wrow = (const float4*)(w_in + (size_t)cur * D_IN);
        float part = 0.f;
#pragma unroll
        for (int c = 0; c < 8; c++) {
            float4 wc = wrow[lane + 64 * c];
            part += wc.x * xf[c * 4 + 0]; part += wc.y * xf[c * 4 + 1];
            part += wc.z * xf[c * 4 + 2]; part += wc.w * xf[c * 4 + 3];
        }
#pragma unroll
        for (int off = 32; off >= 1; off >>= 1) part += __shfl_xor(part, off, 64);
        const float score = part;
        const float g = 0.5f * score * (1.0f + erff(score * 0.70710678118654752f));
        if (TRANSPOSED) {
            const float4* orow = (const float4*)(w_out + (size_t)cur * D_OUT);
#pragma unroll
            for (int c = 0; c < 8; c++) {
                float4 oc = orow[lane + 64 * c];
                acc[c * 4 + 0] += g * oc.x; acc[c * 4 + 1] += g * oc.y;
                acc[c * 4 + 2] += g * oc.z; acc[c * 4 + 3] += g * oc.w;
            }
        } else {
#pragma unroll
            for (int c = 0; c < 8; c++)
#pragma unroll
                for (int k = 0; k < 4; k++) {
                    const int j = (lane + 64 * c) * 4 + k;
                    acc[c * 4 + k] += g * w_out[(size_t)j * N_NODES + cur];
                }
        }
        cur = 2 * cur + 1 + (score >= 0.f ? 1 : 0);
    }
    float4* outrow = (float4*)(out + (size_t)token * D_OUT);
#pragma unroll
    for (int c = 0; c < 8; c++) {
        float4 o;
        o.x = acc[c * 4 + 0]; o.y = acc[c * 4 + 1];
        o.z = acc[c * 4 + 2]; o.w = acc[c * 4 + 3];
        outrow[lane + 64 * c] = o;
    }
}

extern "C" void kernel_launch(void* const* d_in, const int* in_sizes, int n_in,
                              void* d_out, int out_size, void* d_ws, size_t ws_size,
                              hipStream_t stream) {
    (void)in_sizes; (void)n_in; (void)out_size;
    const float* x     = (const float*)d_in[0];
    const float* w_in  = (const float*)d_in[1];
    const float* w_out = (const float*)d_in[2];
    float* out = (float*)d_out;

    const size_t wt_bytes   = (size_t)N_NODES * D_OUT * sizeof(float);   // 33.546 MB
    const size_t g_bytes    = (size_t)N_TOK * DEPTHP1 * sizeof(float);   // 393 KB
    const size_t leaf_bytes = (size_t)N_TOK * sizeof(int);
    const size_t ord_bytes  = (size_t)N_TOK * sizeof(int);
    const size_t hist_bytes = (size_t)N_LEAF * sizeof(int);
    const size_t cnt_bytes  = (size_t)N_LEAF * sizeof(int);
    const size_t offs_bytes = (size_t)(N_LEAF + 1) * sizeof(int);
    const size_t gs_bytes   = g_bytes;                                   // g_sorted
    const size_t lfs_bytes  = (size_t)N_TOK * sizeof(int);               // lf_sorted
    const size_t need = wt_bytes + g_bytes + leaf_bytes + ord_bytes +
                        hist_bytes + cnt_bytes + offs_bytes + gs_bytes +
                        lfs_bytes + 64;

    if (ws_size >= need) {
        char* p = (char*)d_ws;
        float* w_out_t  = (float*)p;  p += wt_bytes;
        float* g_all    = (float*)p;  p += g_bytes;
        int*   leaf     = (int*)p;    p += leaf_bytes;
        int*   order    = (int*)p;    p += ord_bytes;
        int*   hist     = (int*)p;    p += hist_bytes;   // hist+cnt contiguous
        int*   cnt      = (int*)p;    p += cnt_bytes;
        int*   offsets  = (int*)p;    p += offs_bytes;
        float* g_sorted = (float*)p;  p += gs_bytes;
        int*   lf_sorted= (int*)p;

        init_counts<<<(2 * N_LEAF + 255) / 256, 256, 0, stream>>>(hist);
        transpose_wout64<<<dim3((N_NODES + 63) / 64, D_OUT / 64), dim3(64, 4),
                           0, stream>>>(w_out, w_out_t);
        phaseA_gl<<<N_TOK, 64, 0, stream>>>(x, w_in, g_all, leaf, hist);
        scan2048<<<1, 256, 0, stream>>>(hist, offsets);
        scatter_tokens<<<N_TOK / 256, 256, 0, stream>>>(leaf, offsets, cnt,
                                                        g_all, order, g_sorted,
                                                        lf_sorted);
        phaseB_cols<<<2048, 256, 0, stream>>>(w_out_t, g_sorted, order,
                                              lf_sorted, out);
    } else if (ws_size >= wt_bytes) {
        float* w_out_t = (float*)d_ws;
        transpose_wout64<<<dim3((N_NODES + 63) / 64, D_OUT / 64), dim3(64, 4),
                           0, stream>>>(w_out, w_out_t);
        fff_fused<true><<<N_TOK / 4, 256, 0, stream>>>(x, w_in, w_out_t, out);
    } else {
        fff_fused<false><<<N_TOK / 4, 256, 0, stream>>>(x, w_in, w_out, out);
    }
}

// Round 8
// 224.890 us; speedup vs baseline: 1.5029x; 1.0711x over previous
//
#include <hip/hip_runtime.h>

// FFF tree-routing MLP, MI355X — fp32 I/O. Round 13: pipeline compaction.
//
// R12 post-mortem: phaseA_gl (global_load_lds, 1-wave blocks) = 84.9us,
// WORSE than R11's LDS-x phaseA (67.7us): occupancy 21%, full vmcnt(0)
// serializes. Five structurally different phaseA inner loops all land
// 67-115us -> phaseA floor = w-row LLC traffic (786MB @ ~12TB/s); inner-loop
// surgery closed. The real target: total 240.9 - phaseA 84.9 = 156us across
// 6 small dispatches; kernel-time accounting leaves ~75us of launch gaps
// (6 x ~12us). R13: 7 kernels -> 4, no math changes. (1) init folds into
// transpose; (2) scan2048 folds into scatter (32 blocks each redundantly
// scan hist[2048] in LDS, ~3us, offsets never materialize); (3) phaseA =
// R11 verbatim; phaseB_cols = R12 verbatim. All FP orders bit-identical.

#define D_IN    2048
#define D_OUT   2048
#define DEPTHP1 12
#define N_NODES 4095
#define N_TOK   8192
#define N_LEAF  2048

typedef float f4 __attribute__((ext_vector_type(4)));

// ---------------- K1: transpose w_out + zero hist/cnt ----------------------
__global__ __launch_bounds__(256) void transpose_wout64z(
    const float* __restrict__ in, float* __restrict__ out,
    int* __restrict__ hc /* hist[2048] cnt[2048] contiguous */) {
    __shared__ float tile[64][65];
    const int fb = blockIdx.y * 64 + blockIdx.x;     // 0..2047
    const int tx = threadIdx.x;                      // 0..63
    const int ty = threadIdx.y;                      // 0..3
    if (fb < 16) {
        const int i = fb * 256 + ty * 64 + tx;       // 0..4095 = 2*N_LEAF
        hc[i] = 0;
    }
    const int n0 = blockIdx.x * 64;
    const int j0 = blockIdx.y * 64;
    const int n = n0 + tx;
#pragma unroll
    for (int k = 0; k < 16; k++) {
        const int r = ty * 16 + k;                   // 0..63
        if (n < N_NODES) tile[r][tx] = in[(size_t)(j0 + r) * N_NODES + n];
    }
    __syncthreads();
#pragma unroll
    for (int k = 0; k < 16; k++) {
        const int r = ty * 16 + k;
        const int nn = n0 + r;
        if (nn < N_NODES) out[(size_t)nn * D_OUT + (j0 + tx)] = tile[tx][r];
    }
}

// ---------------- K2: phase A — path + gelu(logit) per token (R11-proven) --
__global__ __launch_bounds__(256) void phaseA(
    const float* __restrict__ x,      // [N_TOK, D_IN]
    const float* __restrict__ w_in,   // [N_NODES, D_IN]
    float* __restrict__ g_all,        // [N_TOK, 12]
    int* __restrict__ leaf,           // [N_TOK]
    int* __restrict__ hist) {         // [N_LEAF]
    extern __shared__ float xs[];     // 4 waves x 2048 floats = 32 KB
    const int wave  = threadIdx.x >> 6;
    const int lane  = threadIdx.x & 63;
    const int token = blockIdx.x * 4 + wave;

    // Stage this token's x row into the wave-private LDS slice (once).
    float4* xw = (float4*)(xs) + wave * (D_IN / 4);
    const float4* xrow = (const float4*)(x + (size_t)token * D_IN);
#pragma unroll
    for (int c = 0; c < 8; c++) xw[lane + 64 * c] = xrow[lane + 64 * c];
    // Same-wave produce->consume; compiler inserts lgkmcnt wait. No barrier.

    int cur = 0;
#pragma unroll
    for (int l = 0; l < DEPTHP1; l++) {
        const float4* wrow = (const float4*)(w_in + (size_t)cur * D_IN);
        float p0 = 0.f, p1 = 0.f, p2 = 0.f, p3 = 0.f;
#pragma unroll
        for (int c = 0; c < 8; c++) {
            const float4 wc = wrow[lane + 64 * c];
            const float4 xc = xw[lane + 64 * c];
            float* p = (c < 2) ? &p0 : (c < 4) ? &p1 : (c < 6) ? &p2 : &p3;
            *p += wc.x * xc.x + wc.y * xc.y + wc.z * xc.z + wc.w * xc.w;
        }
        float part = (p0 + p1) + (p2 + p3);
#pragma unroll
        for (int off = 32; off >= 1; off >>= 1)
            part += __shfl_xor(part, off, 64);
        const float score = part;
        // Advance the path first: next-level loads depend only on `cur`.
        cur = 2 * cur + 1 + (score >= 0.f ? 1 : 0);
        const float g = 0.5f * score * (1.0f + erff(score * 0.70710678118654752f));
        if (lane == 0) g_all[token * DEPTHP1 + l] = g;
    }
    if (lane == 0) {
        const int leafid = ((cur - 1) >> 1) - (N_LEAF - 1);  // level-11 node id
        leaf[token] = leafid;
        atomicAdd(&hist[leafid], 1);                         // 2048 bins: spread
    }
}

// ---------------- K3: scatter with fused in-block scan ---------------------
// 32 blocks x 256 threads; each block redundantly scans hist[2048] in LDS
// (offsets never hit global), then scatters its 256 tokens.
__global__ __launch_bounds__(256) void scatter_scan(
    const int* __restrict__ leaf, const int* __restrict__ hist,
    int* __restrict__ cnt, const float* __restrict__ g_all,
    int* __restrict__ order, float* __restrict__ g_sorted,
    int* __restrict__ lf_sorted) {
    __shared__ int voff[N_LEAF];       // exclusive offsets, 8 KB
    __shared__ int partial[256];
    const int t = threadIdx.x;
    int v[8];
    int sum = 0;
#pragma unroll
    for (int k = 0; k < 8; k++) {
        v[k] = hist[t * 8 + k];
        sum += v[k];
    }
    partial[t] = sum;
    __syncthreads();
    for (int off = 1; off < 256; off <<= 1) {
        const int pv = partial[t];
        const int po = (t >= off) ? partial[t - off] : 0;
        __syncthreads();
        partial[t] = pv + po;
        __syncthreads();
    }
    int base = (t > 0) ? partial[t - 1] : 0;
#pragma unroll
    for (int k = 0; k < 8; k++) {
        voff[t * 8 + k] = base;
        base += v[k];
    }
    __syncthreads();

    const int tok = blockIdx.x * 256 + t;          // N_TOK == 32*256 exactly
    const int lf  = leaf[tok];
    const int pos = voff[lf] + atomicAdd(&cnt[lf], 1);
    order[pos] = tok;
    lf_sorted[pos] = lf;
#pragma unroll
    for (int l = 0; l < DEPTHP1; l++)
        g_sorted[(size_t)pos * DEPTHP1 + l] = g_all[(size_t)tok * DEPTHP1 + l];
}

// ---------------- K4: phase B — sorted-order col-tile streaming (R12) ------
// 2048 blocks = 8 XCDs x {128 token-ranges(8) x 2 col-halves}. XCD k owns
// sorted positions [k*1024,(k+1)*1024): a 256-leaf subtree whose row-slice
// union fits k's 4MB L2. Within a leaf-run the 12 row-f4s live in registers.
__global__ __launch_bounds__(256) void phaseB_cols(
    const float* __restrict__ w_out_t,   // [N_NODES, D_OUT]
    const float* __restrict__ g_sorted,  // [N_TOK, 12] leaf-sorted, gelu'd
    const int* __restrict__ order,       // [N_TOK]
    const int* __restrict__ lf_sorted,   // [N_TOK]
    float* __restrict__ out) {           // [N_TOK, D_OUT]
    const int b   = blockIdx.x;
    const int xcd = b & 7;
    const int j   = b >> 3;               // 0..255
    const int tr  = xcd * 128 + (j >> 1); // 0..1023 token-range (8 tokens)
    const int ct  = j & 1;                // column half
    const int t   = threadIdx.x;          // f4 column within half
    const size_t coff = (size_t)ct * 1024 + (size_t)t * 4;

    const int start = tr * 8;
    const int end   = start + 8;

    int pos = start;
    while (pos < end) {
        const int lf = lf_sorted[pos];    // block-uniform (scalar)
        const int L  = lf + N_LEAF;       // 1-based leaf heap index
        f4 w[DEPTHP1];                    // this leaf's 12 row-f4s, in VGPRs
#pragma unroll
        for (int l = 0; l < DEPTHP1; l++) {
            const int node = (L >> (DEPTHP1 - 1 - l)) - 1;
            w[l] = *(const f4*)(w_out_t + (size_t)node * D_OUT + coff);
        }
        do {
            const int tok = order[pos];                       // scalar
            const float* gp = g_sorted + (size_t)pos * DEPTHP1;
            f4 acc = {0.f, 0.f, 0.f, 0.f};
#pragma unroll
            for (int l = 0; l < DEPTHP1; l++)
                acc += gp[l] * w[l];      // ascending l: same FP order as R11
            __builtin_nontemporal_store(
                acc, (f4*)(out + (size_t)tok * D_OUT + coff));
            pos++;
        } while (pos < end && lf_sorted[pos] == lf);
    }
}

// ---------------- Fallback: round-2 fused kernel (ws too small) ------------
__global__ __launch_bounds__(256) void transpose_wout64(
    const float* __restrict__ in, float* __restrict__ out) {
    __shared__ float tile[64][65];
    const int n0 = blockIdx.x * 64;
    const int j0 = blockIdx.y * 64;
    const int tx = threadIdx.x;
    const int ty = threadIdx.y;
    const int n = n0 + tx;
#pragma unroll
    for (int k = 0; k < 16; k++) {
        const int r = ty * 16 + k;
        if (n < N_NODES) tile[r][tx] = in[(size_t)(j0 + r) * N_NODES + n];
    }
    __syncthreads();
#pragma unroll
    for (int k = 0; k < 16; k++) {
        const int r = ty * 16 + k;
        const int nn = n0 + r;
        if (nn < N_NODES) out[(size_t)nn * D_OUT + (j0 + tx)] = tile[tx][r];
    }
}

template <bool TRANSPOSED>
__global__ __launch_bounds__(256) void fff_fused(
    const float* __restrict__ x, const float* __restrict__ w_in,
    const float* __restrict__ w_out, float* __restrict__ out) {
    const int wave  = threadIdx.x >> 6;
    const int lane  = threadIdx.x & 63;
    const int token = blockIdx.x * 4 + wave;
    const float4* xrow = (const float4*)(x + (size_t)token * D_IN);
    float xf[32];
#pragma unroll
    for (int c = 0; c < 8; c++) {
        float4 xc = xrow[lane + 64 * c];
        xf[c * 4 + 0] = xc.x; xf[c * 4 + 1] = xc.y;
        xf[c * 4 + 2] = xc.z; xf[c * 4 + 3] = xc.w;
    }
    float acc[32];
#pragma unroll
    for (int k = 0; k < 32; k++) acc[k] = 0.f;
    int cur = 0;
#pragma unroll
    for (int l = 0; l < DEPTHP1; l++) {
        const float4* wrow = (const float4*)(w_in + (size_t)cur * D_IN);
        float part = 0.f;
#pragma unroll
        for (int c = 0; c < 8; c++) {
            float4 wc = wrow[lane + 64 * c];
            part += wc.x * xf[c * 4 + 0]; part += wc.y * xf[c * 4 + 1];
            part += wc.z * xf[c * 4 + 2]; part += wc.w * xf[c * 4 + 3];
        }
#pragma unroll
        for (int off = 32; off >= 1; off >>= 1) part += __shfl_xor(part, off, 64);
        const float score = part;
        const float g = 0.5f * score * (1.0f + erff(score * 0.70710678118654752f));
        if (TRANSPOSED) {
            const float4* orow = (const float4*)(w_out + (size_t)cur * D_OUT);
#pragma unroll
            for (int c = 0; c < 8; c++) {
                float4 oc = orow[lane + 64 * c];
                acc[c * 4 + 0] += g * oc.x; acc[c * 4 + 1] += g * oc.y;
                acc[c * 4 + 2] += g * oc.z; acc[c * 4 + 3] += g * oc.w;
            }
        } else {
#pragma unroll
            for (int c = 0; c < 8; c++)
#pragma unroll
                for (int k = 0; k < 4; k++) {
                    const int j = (lane + 64 * c) * 4 + k;
                    acc[c * 4 + k] += g * w_out[(size_t)j * N_NODES + cur];
                }
        }
        cur = 2 * cur + 1 + (score >= 0.f ? 1 : 0);
    }
    float4* outrow = (float4*)(out + (size_t)token * D_OUT);
#pragma unroll
    for (int c = 0; c < 8; c++) {
        float4 o;
        o.x = acc[c * 4 + 0]; o.y = acc[c * 4 + 1];
        o.z = acc[c * 4 + 2]; o.w = acc[c * 4 + 3];
        outrow[lane + 64 * c] = o;
    }
}

extern "C" void kernel_launch(void* const* d_in, const int* in_sizes, int n_in,
                              void* d_out, int out_size, void* d_ws, size_t ws_size,
                              hipStream_t stream) {
    (void)in_sizes; (void)n_in; (void)out_size;
    const float* x     = (const float*)d_in[0];
    const float* w_in  = (const float*)d_in[1];
    const float* w_out = (const float*)d_in[2];
    float* out = (float*)d_out;

    const size_t wt_bytes   = (size_t)N_NODES * D_OUT * sizeof(float);   // 33.546 MB
    const size_t g_bytes    = (size_t)N_TOK * DEPTHP1 * sizeof(float);   // 393 KB
    const size_t leaf_bytes = (size_t)N_TOK * sizeof(int);
    const size_t ord_bytes  = (size_t)N_TOK * sizeof(int);
    const size_t hist_bytes = (size_t)N_LEAF * sizeof(int);
    const size_t cnt_bytes  = (size_t)N_LEAF * sizeof(int);
    const size_t gs_bytes   = g_bytes;                                   // g_sorted
    const size_t lfs_bytes  = (size_t)N_TOK * sizeof(int);               // lf_sorted
    const size_t need = wt_bytes + g_bytes + leaf_bytes + ord_bytes +
                        hist_bytes + cnt_bytes + gs_bytes + lfs_bytes + 64;

    if (ws_size >= need) {
        char* p = (char*)d_ws;
        float* w_out_t  = (float*)p;  p += wt_bytes;
        float* g_all    = (float*)p;  p += g_bytes;
        int*   leaf     = (int*)p;    p += leaf_bytes;
        int*   order    = (int*)p;    p += ord_bytes;
        int*   hist     = (int*)p;    p += hist_bytes;   // hist+cnt contiguous
        int*   cnt      = (int*)p;    p += cnt_bytes;
        float* g_sorted = (float*)p;  p += gs_bytes;
        int*   lf_sorted= (int*)p;

        transpose_wout64z<<<dim3(64, 32), dim3(64, 4), 0, stream>>>(
            w_out, w_out_t, hist);
        phaseA<<<N_TOK / 4, 256, 4 * D_IN * sizeof(float), stream>>>(
            x, w_in, g_all, leaf, hist);
        scatter_scan<<<N_TOK / 256, 256, 0, stream>>>(leaf, hist, cnt, g_all,
                                                      order, g_sorted, lf_sorted);
        phaseB_cols<<<2048, 256, 0, stream>>>(w_out_t, g_sorted, order,
                                              lf_sorted, out);
    } else if (ws_size >= wt_bytes) {
        float* w_out_t = (float*)d_ws;
        transpose_wout64<<<dim3((N_NODES + 63) / 64, D_OUT / 64), dim3(64, 4),
                           0, stream>>>(w_out, w_out_t);
        fff_fused<true><<<N_TOK / 4, 256, 0, stream>>>(x, w_in, w_out_t, out);
    } else {
        fff_fused<false><<<N_TOK / 4, 256, 0, stream>>>(x, w_in, w_out, out);
    }
}